// Round 2
// baseline (1662.653 us; speedup 1.0000x reference)
//
#include <hip/hip_runtime.h>

typedef __bf16 bf16x8 __attribute__((ext_vector_type(8)));
typedef float  f32x4  __attribute__((ext_vector_type(4)));

__device__ __forceinline__ unsigned short f2bf(float x){
  return __builtin_bit_cast(unsigned short, (__bf16)x);   // HW v_cvt on gfx950, RNE
}

// ---------------------------------------------------------------------------
// Weight pack: MFMA B-fragment order (bf16), lane holds B[k=kt*32+(lane>>4)*8+jj][n=lane&15].
// Gate weights are PRE-SCALED by -log2(e) (i,f,o) or -2*log2(e) (g) so the MFMA
// accumulator is directly the exp2() argument for the activations.
// Frag sections: [0,48) encL0 (ntile*3+kt, K: x 0..16|pad|h 32..96)
//                [48,112) encL1 (ntile*4+kt, K: h0 0..64|h1 64..128)
//                [112,160) decL0, [160,224) decL1, [224,226) W_out (N=4 padded to 16, K=64)
// ---------------------------------------------------------------------------
__global__ void pack_weights(const float* __restrict__ eWih0, const float* __restrict__ eWhh0,
                             const float* __restrict__ eWih1, const float* __restrict__ eWhh1,
                             const float* __restrict__ dWih0, const float* __restrict__ dWhh0,
                             const float* __restrict__ dWih1, const float* __restrict__ dWhh1,
                             const float* __restrict__ Wout,
                             unsigned short* __restrict__ out){
  int t = blockIdx.x * 256 + threadIdx.x;
  if (t >= 226 * 64) return;
  int lane = t & 63;
  int f    = t >> 6;
  unsigned short vals[8];
  if (f >= 224){                                       // W_out frags (NOT scaled)
    int kt = f - 224, n = lane & 15;
#pragma unroll
    for (int jj = 0; jj < 8; jj++){
      int k = kt * 32 + (lane >> 4) * 8 + jj;
      vals[jj] = (n < 4) ? f2bf(Wout[n * 64 + k]) : (unsigned short)0;
    }
  } else {
    const float *Wih, *Whh; int kx, ntile, kt;
    if (f < 48)       { Wih=eWih0; Whh=eWhh0; kx=16; ntile=f/3;        kt=f%3; }
    else if (f < 112) { Wih=eWih1; Whh=eWhh1; kx=64; ntile=(f-48)/4;   kt=(f-48)%4; }
    else if (f < 160) { Wih=dWih0; Whh=dWhh0; kx=16; ntile=(f-112)/3;  kt=(f-112)%3; }
    else              { Wih=dWih1; Whh=dWhh1; kx=64; ntile=(f-160)/4;  kt=(f-160)%4; }
    int n    = ntile * 16 + (lane & 15);
    int hoff = (kx == 16) ? 32 : 64;
    // gate index = n/64 = ntile/4; gates i,f,o get -log2(e), gate g gets -2*log2(e)
    float scale = ((ntile >> 2) == 2) ? -2.88539008f : -1.44269504f;
#pragma unroll
    for (int jj = 0; jj < 8; jj++){
      int k = kt * 32 + (lane >> 4) * 8 + jj;
      float v;
      if (k < kx)        v = Wih[n * kx + k];
      else if (k < hoff) v = 0.0f;
      else               v = Whh[n * 64 + (k - hoff)];
      vals[jj] = f2bf(v * scale);
    }
  }
  uint4 o;
  o.x = (unsigned)vals[0] | ((unsigned)vals[1] << 16);
  o.y = (unsigned)vals[2] | ((unsigned)vals[3] << 16);
  o.z = (unsigned)vals[4] | ((unsigned)vals[5] << 16);
  o.w = (unsigned)vals[6] | ((unsigned)vals[7] << 16);
  ((uint4*)out)[f * 64 + lane] = o;
}

// A-layout (16-row subtile): elem(m,k) at ((k>>5)*64 + (m | (((k>>3)&3)<<4)))*8 + (k&7)
__device__ __forceinline__ void write_h(unsigned short* buf, int k, int quad,
                                        const unsigned short* h){
  unsigned short* p = buf + (((k >> 5) * 64) + quad * 4 + (((k >> 3) & 3) << 4)) * 8 + (k & 7);
#pragma unroll
  for (int e = 0; e < 4; e++) p[e * 8] = h[e];
}

__device__ __forceinline__ void load_frags(const unsigned short* __restrict__ pw,
                                           int base0, int base1, int w, int lane,
                                           bf16x8 (&B0)[3][4], bf16x8 (&B1)[4][4]){
#pragma unroll
  for (int g = 0; g < 4; g++){
    int nt = 4 * g + w;
#pragma unroll
    for (int kt = 0; kt < 3; kt++)
      B0[kt][g] = *(const bf16x8*)(pw + (((long)(base0 + nt * 3 + kt)) * 64 + lane) * 8);
#pragma unroll
    for (int kt = 0; kt < 4; kt++)
      B1[kt][g] = *(const bf16x8*)(pw + (((long)(base1 + nt * 4 + kt)) * 64 + lane) * 8);
  }
}

// One LSTM cell step for 16 rows (one subtile), this wave's 16 j's.
// acc[gate] arrives pre-scaled (exp2-ready). Fused reciprocals:
//   sig(i)*tanh(g) = (1-eg) / ((1+ei)(1+eg)),  eg=e^{-2g}, ei=e^{-i}
//   sig(o)*tanh(c) = (ec-1) / ((1+eo)(1+ec)),  ec=e^{2c}
// c is kept pre-scaled by 2*log2(e) so exp2(c2) = e^{2c} directly.
template<int KT>
__device__ __forceinline__ void cell_compute(const unsigned short* __restrict__ A,
                                             const bf16x8 (&B)[KT][4],
                                             const float (&bias)[4],
                                             float (&c)[4],
                                             unsigned short (&hout)[4],
                                             int lane){
  f32x4 acc[4];
#pragma unroll
  for (int g = 0; g < 4; g++){
    f32x4 b = {bias[g], bias[g], bias[g], bias[g]};
    acc[g] = b;
  }
#pragma unroll
  for (int kt = 0; kt < KT; kt++){
    bf16x8 a0 = *(const bf16x8*)(A + (kt * 64 + lane) * 8);
#pragma unroll
    for (int g = 0; g < 4; g++)
      acc[g] = __builtin_amdgcn_mfma_f32_16x16x32_bf16(a0, B[kt][g], acc[g], 0, 0, 0);
  }
#pragma unroll
  for (int e = 0; e < 4; e++){
    float ei = __builtin_amdgcn_exp2f(acc[0][e]);     // e^{-i}
    float ef = __builtin_amdgcn_exp2f(acc[1][e]);     // e^{-f}
    float eg = __builtin_amdgcn_exp2f(acc[2][e]);     // e^{-2g}
    float eo = __builtin_amdgcn_exp2f(acc[3][e]);     // e^{-o}
    float rf  = __builtin_amdgcn_rcpf(1.0f + ef);                   // sig(f)
    float rig = __builtin_amdgcn_rcpf((1.0f + ei) * (1.0f + eg));
    float c2  = fmaf(c[e], rf, fmaf(-2.88539008f, eg, 2.88539008f) * rig);
    c[e] = c2;
    float ec  = __builtin_amdgcn_exp2f(c2);           // e^{2c}
    float rot = __builtin_amdgcn_rcpf((1.0f + eo) * (1.0f + ec));
    hout[e] = f2bf((ec - 1.0f) * rot);                // sig(o)*tanh(c)
  }
}

// ---------------------------------------------------------------------------
// Main: one block = 16 batch rows (grid 1024 -> 4 blocks/CU for latency hiding).
// Full encoder (1 barrier/step, layer-skewed) + decoder (4 barriers/step).
// 4 waves; wave w owns j-slice [16w,16w+16) for all 4 gates.
// ---------------------------------------------------------------------------
__global__ __launch_bounds__(256, 4)
void lstm_main(const float* __restrict__ src, const float* __restrict__ trg,
               const float* __restrict__ W_in, const float* __restrict__ b_in,
               const float* __restrict__ eb0, const float* __restrict__ eb1,
               const float* __restrict__ db0, const float* __restrict__ db1,
               const float* __restrict__ bout,
               const unsigned short* __restrict__ pw,
               float* __restrict__ out){
  __shared__ __align__(16) unsigned short A0[2][1536];   // ping-pong, K=96
  __shared__ __align__(16) unsigned short A1[2][2048];   // K=128
  __shared__ __align__(16) float xsrc[2][64];            // per-step x ping-pong (16 rows x 4)
  __shared__ __align__(16) float xfb[64];                // decoder feedback x
  __shared__ __align__(16) unsigned short sWoutF[1024];  // W_out B-frags (2 x 64 x 8)

  const int tid  = threadIdx.x;
  const int lane = tid & 63;
  const int w    = tid >> 6;
  const int quad = lane >> 4;
  const int l16  = lane & 15;
  const int j    = 16 * w + l16;
  const int rowg0 = blockIdx.x * 16;
  const int mm   = tid & 15;                  // x-proj: this thread's m-unit
  const int xr   = tid >> 4;                  // x-proj: row (0..15)

  // ---- staging ----
  {
    uint4 z; z.x = z.y = z.z = z.w = 0u;
    uint4* a0p = (uint4*)A0;                  // 384 uint4
    uint4* a1p = (uint4*)A1;                  // 512 uint4
    for (int i = tid; i < 384; i += 256) a0p[i] = z;
    for (int i = tid; i < 512; i += 256) a1p[i] = z;
    if (tid < 128) ((uint4*)sWoutF)[tid] = ((const uint4*)pw)[224 * 64 + tid];
    if (tid < 64)  xsrc[0][tid] = src[(long)(rowg0 + (tid >> 2)) * 256 + (tid & 3)];
  }
  const float4 wv = *(const float4*)&W_in[mm * 4];
  const float  bin = b_in[mm];

  bf16x8 B0[3][4], B1[4][4];
  float bias0[4], bias1[4];
  float c0[4] = {0,0,0,0}, c1[4] = {0,0,0,0};
  load_frags(pw, 0, 48, w, lane, B0, B1);
#pragma unroll
  for (int g = 0; g < 4; g++){
    int n = 64*g + j;
    float s = (g == 2) ? -2.88539008f : -1.44269504f;   // match weight pre-scale
    bias0[g] = eb0[n] * s; bias1[g] = eb1[n] * s;
  }
  __syncthreads();

  unsigned short h0r[4], h1r[4];
  const int xoff = (xr | ((mm >> 3) << 4)) * 8 + (mm & 7);   // A-layout slot for k=mm

  // ================= encoder: 1 barrier/step (cell1 skewed by 1) =================
  for (int t = 0; t < 64; t++){
    int cur = t & 1, nxt = cur ^ 1;
    float xv;
    if (tid < 64)
      xv = src[(long)(rowg0 + (tid >> 2)) * 256 + ((t == 63 ? 63 : t + 1) << 2) + (tid & 3)];
    { // x-projection for row xr
      float4 x0 = *(const float4*)&xsrc[cur][xr * 4];
      float m0 = bin + x0.x*wv.x + x0.y*wv.y + x0.z*wv.z + x0.w*wv.w;
      A0[cur][xoff] = f2bf(m0);
    }
    if (tid < 64) xsrc[nxt][tid] = xv;
    __syncthreads();
    // cell0(t)
    cell_compute<3>(&A0[cur][0], B0, bias0, c0, h0r, lane);
    write_h(&A0[nxt][0], 32 + j, quad, h0r);   // recurrent h0
    write_h(&A1[cur][0],      j, quad, h0r);   // feed layer 1
    // cell1(t-1) — inputs written during iter t-1, visible since barrier above
    if (t > 0){
      cell_compute<4>(&A1[nxt][0], B1, bias1, c1, h1r, lane);
      write_h(&A1[cur][0], 64 + j, quad, h1r); // recurrent h1
    }
  }
  __syncthreads();
  // flush cell1(63): reads A1[1], writes recurrent into A1[0] for decoder t=0
  cell_compute<4>(&A1[1][0], B1, bias1, c1, h1r, lane);
  write_h(&A1[0][0], 64 + j, quad, h1r);

  // ================= decoder =================
  load_frags(pw, 112, 160, w, lane, B0, B1);
#pragma unroll
  for (int g = 0; g < 4; g++){
    int n = 64*g + j;
    float s = (g == 2) ? -2.88539008f : -1.44269504f;
    bias0[g] = db0[n] * s; bias1[g] = db1[n] * s;
  }
  const float bo = (w == 0 && l16 < 4) ? bout[l16] : 0.0f;
  if (tid < 64) xfb[tid] = trg[(long)(rowg0 + (tid >> 2)) * 256 + (tid & 3)];
  __syncthreads();

  for (int t = 0; t < 64; t++){
    int cur = t & 1, nxt = cur ^ 1;
    float tpre[4];
    if (w == 0 && l16 < 4){
#pragma unroll
      for (int e = 0; e < 4; e++)
        tpre[e] = trg[(long)(rowg0 + quad * 4 + e) * 256 + t * 4 + l16];
    }
    { // m = x @ W_in^T + b_in
      float4 x0 = *(const float4*)&xfb[xr * 4];
      float m0 = bin + x0.x*wv.x + x0.y*wv.y + x0.z*wv.z + x0.w*wv.w;
      A0[cur][xoff] = f2bf(m0);
    }
    __syncthreads();                       // barA
    cell_compute<3>(&A0[cur][0], B0, bias0, c0, h0r, lane);
    write_h(&A0[nxt][0], 32 + j, quad, h0r);
    write_h(&A1[cur][0],      j, quad, h0r);
    __syncthreads();                       // barB
    cell_compute<4>(&A1[cur][0], B1, bias1, c1, h1r, lane);
    write_h(&A1[nxt][0], 64 + j, quad, h1r);
    __syncthreads();                       // barC: h2 visible
    if (w == 0){                           // MFMA out-projection (16 rows)
      const unsigned short* Ah = &A1[nxt][0];
      bf16x8 a2 = *(const bf16x8*)(Ah + (2 * 64 + lane) * 8);
      bf16x8 a3 = *(const bf16x8*)(Ah + (3 * 64 + lane) * 8);
      bf16x8 bw0 = *(const bf16x8*)(sWoutF + lane * 8);
      bf16x8 bw1 = *(const bf16x8*)(sWoutF + 512 + lane * 8);
      f32x4 po = {bo, bo, bo, bo};
      po = __builtin_amdgcn_mfma_f32_16x16x32_bf16(a2, bw0, po, 0, 0, 0);
      po = __builtin_amdgcn_mfma_f32_16x16x32_bf16(a3, bw1, po, 0, 0, 0);
      if (l16 < 4){
#pragma unroll
        for (int e = 0; e < 4; e++){
          int row = quad * 4 + e;
          float v = po[e] + tpre[e];
          out[(long)(rowg0 + row) * 256 + t * 4 + l16] = v;
          xfb[row * 4 + l16] = v;
        }
      }
    }
    __syncthreads();                       // barD: xfb visible
  }
}

extern "C" void kernel_launch(void* const* d_in, const int* in_sizes, int n_in,
                              void* d_out, int out_size, void* d_ws, size_t ws_size,
                              hipStream_t stream){
  (void)n_in; (void)out_size; (void)ws_size;
  const float* src   = (const float*)d_in[0];
  const float* trg   = (const float*)d_in[1];
  const float* W_in  = (const float*)d_in[2];
  const float* b_in  = (const float*)d_in[3];
  const float* eWih0 = (const float*)d_in[4];
  const float* eWhh0 = (const float*)d_in[5];
  const float* eb0   = (const float*)d_in[6];
  const float* eWih1 = (const float*)d_in[7];
  const float* eWhh1 = (const float*)d_in[8];
  const float* eb1   = (const float*)d_in[9];
  const float* dWih0 = (const float*)d_in[10];
  const float* dWhh0 = (const float*)d_in[11];
  const float* db0   = (const float*)d_in[12];
  const float* dWih1 = (const float*)d_in[13];
  const float* dWhh1 = (const float*)d_in[14];
  const float* db1   = (const float*)d_in[15];
  const float* Wout  = (const float*)d_in[16];
  const float* bout  = (const float*)d_in[17];
  unsigned short* pw = (unsigned short*)d_ws;          // needs 231,424 bytes

  pack_weights<<<57, 256, 0, stream>>>(eWih0, eWhh0, eWih1, eWhh1,
                                       dWih0, dWhh0, dWih1, dWhh1, Wout, pw);

  int B    = in_sizes[0] / 256;                        // S*I = 256
  int nblk = B / 16;
  lstm_main<<<nblk, 256, 0, stream>>>(src, trg, W_in, b_in, eb0, eb1, db0, db1,
                                      bout, pw, (float*)d_out);
}

// Round 3
// 503.978 us; speedup vs baseline: 3.2991x; 3.2991x over previous
//
#include <hip/hip_runtime.h>

typedef __bf16 bf16x8 __attribute__((ext_vector_type(8)));
typedef float  f32x4  __attribute__((ext_vector_type(4)));

__device__ __forceinline__ unsigned short f2bf(float x){
  return __builtin_bit_cast(unsigned short, (__bf16)x);   // HW v_cvt on gfx950, RNE
}

// ---------------------------------------------------------------------------
// Weight pack: MFMA B-fragment order (bf16), lane holds B[k=kt*32+(lane>>4)*8+jj][n=lane&15].
// Gate weights PRE-SCALED by -log2(e) (i,f,o) or -2*log2(e) (g) so the MFMA
// accumulator is directly the exp2() argument.
// Sections: [0,48)    encL0 (ntile*3+kt, K: x 0..16|pad|h 32..96)
//           [48,112)  encL1 (ntile*4+kt, K: h0 0..64|h1 64..128)
//           [112,192) decL0 (ntile*5+kt, K: m 0..16|pad|h0 32..96|h1-fold 96..160)
//                     kt 3,4 hold Wx1 = dWih0 @ W_in @ W_out  (feedback fold)
//           [192,256) decL1 (ntile*4+kt)
//           [256,258) W_out (N=4 padded to 16, K=64), unscaled
// ---------------------------------------------------------------------------
__global__ void pack_weights(const float* __restrict__ eWih0, const float* __restrict__ eWhh0,
                             const float* __restrict__ eWih1, const float* __restrict__ eWhh1,
                             const float* __restrict__ dWih0, const float* __restrict__ dWhh0,
                             const float* __restrict__ dWih1, const float* __restrict__ dWhh1,
                             const float* __restrict__ Wout,  const float* __restrict__ W_in,
                             unsigned short* __restrict__ out){
  int t = blockIdx.x * 256 + threadIdx.x;
  if (t >= 258 * 64) return;
  int lane = t & 63;
  int f    = t >> 6;
  unsigned short vals[8];
  if (f >= 256){                                       // W_out frags (NOT scaled)
    int kt = f - 256, n = lane & 15;
#pragma unroll
    for (int jj = 0; jj < 8; jj++){
      int k = kt * 32 + (lane >> 4) * 8 + jj;
      vals[jj] = (n < 4) ? f2bf(Wout[n * 64 + k]) : (unsigned short)0;
    }
  } else {
    const float *Wih, *Whh; int kx, ntile, kt, nkt;
    if (f < 48)       { Wih=eWih0; Whh=eWhh0; kx=16; nkt=3; ntile=f/3;        kt=f%3; }
    else if (f < 112) { Wih=eWih1; Whh=eWhh1; kx=64; nkt=4; ntile=(f-48)/4;   kt=(f-48)%4; }
    else if (f < 192) { Wih=dWih0; Whh=dWhh0; kx=16; nkt=5; ntile=(f-112)/5;  kt=(f-112)%5; }
    else              { Wih=dWih1; Whh=dWhh1; kx=64; nkt=4; ntile=(f-192)/4;  kt=(f-192)%4; }
    int n    = ntile * 16 + (lane & 15);
    int hoff = (kx == 16) ? 32 : 64;
    // gate index = ntile/4; gates i,f,o get -log2(e), gate g gets -2*log2(e)
    float scale = ((ntile >> 2) == 2) ? -2.88539008f : -1.44269504f;
#pragma unroll
    for (int jj = 0; jj < 8; jj++){
      int k = kt * 32 + (lane >> 4) * 8 + jj;
      float v;
      if (nkt == 5 && k >= 96){
        // folded feedback weights: Wx1[n][c] = sum_m Wih0[n][m] * (W_in @ W_out)[m][c]
        int c = k - 96;
        float acc = 0.0f;
        for (int m = 0; m < 16; m++){
          float wf = 0.0f;
          for (int i = 0; i < 4; i++) wf += W_in[m * 4 + i] * Wout[i * 64 + c];
          acc += Wih[n * 16 + m] * wf;
        }
        v = acc;
      }
      else if (k < kx)   v = Wih[n * kx + k];
      else if (k < hoff) v = 0.0f;
      else               v = Whh[n * 64 + (k - hoff)];
      vals[jj] = f2bf(v * scale);
    }
  }
  uint4 o;
  o.x = (unsigned)vals[0] | ((unsigned)vals[1] << 16);
  o.y = (unsigned)vals[2] | ((unsigned)vals[3] << 16);
  o.z = (unsigned)vals[4] | ((unsigned)vals[5] << 16);
  o.w = (unsigned)vals[6] | ((unsigned)vals[7] << 16);
  ((uint4*)out)[f * 64 + lane] = o;
}

// A-layout (per 16-row subtile): elem(m,k) at ((k>>5)*64 + (m | (((k>>3)&3)<<4)))*8 + (k&7)
__device__ __forceinline__ void write_h(unsigned short* buf, int k, int quad,
                                        const unsigned short* h){
  unsigned short* p = buf + (((k >> 5) * 64) + quad * 4 + (((k >> 3) & 3) << 4)) * 8 + (k & 7);
#pragma unroll
  for (int e = 0; e < 4; e++) p[e * 8] = h[e];
}

template<int NKT0>
__device__ __forceinline__ void load_frags(const unsigned short* __restrict__ pw,
                                           int base0, int base1, int w, int lane,
                                           bf16x8 (&B0)[5][4], bf16x8 (&B1)[4][4]){
#pragma unroll
  for (int g = 0; g < 4; g++){
    int nt = 4 * g + w;
#pragma unroll
    for (int kt = 0; kt < NKT0; kt++)
      B0[kt][g] = *(const bf16x8*)(pw + (((long)(base0 + nt * NKT0 + kt)) * 64 + lane) * 8);
#pragma unroll
    for (int kt = 0; kt < 4; kt++)
      B1[kt][g] = *(const bf16x8*)(pw + (((long)(base1 + nt * 4 + kt)) * 64 + lane) * 8);
  }
}

// One LSTM cell step for 32 rows (2 row-subtiles of 16), this wave's 16 j's.
// acc arrives exp2-ready (pre-scaled weights). Fused reciprocals:
//   sig(i)*tanh(g) = (1-eg)/((1+ei)(1+eg)),  sig(o)*tanh(c) = (ec-1)/((1+eo)(1+ec))
// c kept pre-scaled by 2*log2(e).
template<int KT, int SZ>
__device__ __forceinline__ void cell_compute(const unsigned short* __restrict__ A,
                                             const bf16x8 (*B)[4],
                                             const float (&bias)[4],
                                             float (&c)[8],
                                             unsigned short (&hout)[8],
                                             int lane){
  f32x4 acc[4][2];
#pragma unroll
  for (int g = 0; g < 4; g++){
    f32x4 b = {bias[g], bias[g], bias[g], bias[g]};
    acc[g][0] = b; acc[g][1] = b;
  }
#pragma unroll
  for (int kt = 0; kt < KT; kt++){
    bf16x8 a0 = *(const bf16x8*)(A +      (kt * 64 + lane) * 8);
    bf16x8 a1 = *(const bf16x8*)(A + SZ + (kt * 64 + lane) * 8);
#pragma unroll
    for (int g = 0; g < 4; g++){
      acc[g][0] = __builtin_amdgcn_mfma_f32_16x16x32_bf16(a0, B[kt][g], acc[g][0], 0, 0, 0);
      acc[g][1] = __builtin_amdgcn_mfma_f32_16x16x32_bf16(a1, B[kt][g], acc[g][1], 0, 0, 0);
    }
  }
#pragma unroll
  for (int rt = 0; rt < 2; rt++){
#pragma unroll
    for (int e = 0; e < 4; e++){
      int idx = rt * 4 + e;
      float ei = __builtin_amdgcn_exp2f(acc[0][rt][e]);
      float ef = __builtin_amdgcn_exp2f(acc[1][rt][e]);
      float eg = __builtin_amdgcn_exp2f(acc[2][rt][e]);
      float eo = __builtin_amdgcn_exp2f(acc[3][rt][e]);
      float rf  = __builtin_amdgcn_rcpf(1.0f + ef);
      float rig = __builtin_amdgcn_rcpf((1.0f + ei) * (1.0f + eg));
      float c2  = fmaf(c[idx], rf, fmaf(-2.88539008f, eg, 2.88539008f) * rig);
      c[idx] = c2;
      float ec  = __builtin_amdgcn_exp2f(c2);
      float rot = __builtin_amdgcn_rcpf((1.0f + eo) * (1.0f + ec));
      hout[idx] = f2bf((ec - 1.0f) * rot);
    }
  }
}

// ---------------------------------------------------------------------------
// Main: one block = 32 batch rows (grid 512 = 2 blocks/CU, all resident).
// Encoder: 1 barrier/step (layer-skewed). Decoder: 2 barriers/step via the
// Wx1 feedback fold; W_out projection runs SKEWED (out(t-1) during step t).
// ---------------------------------------------------------------------------
__global__ __launch_bounds__(256, 2)
void lstm_main(const float* __restrict__ src, const float* __restrict__ trg,
               const float* __restrict__ W_in, const float* __restrict__ b_in,
               const float* __restrict__ eb0, const float* __restrict__ eb1,
               const float* __restrict__ db0, const float* __restrict__ db1,
               const float* __restrict__ bout,
               const unsigned short* __restrict__ pw,
               float* __restrict__ out){
  __shared__ __align__(16) unsigned short A0[2][2][2560];   // ping-pong, 2 subtiles, K=160
  __shared__ __align__(16) unsigned short A1[2][2][2048];   // K=128
  __shared__ __align__(16) float xsrc[2][128];              // encoder x ping-pong
  __shared__ __align__(16) unsigned short sWoutF[1024];     // W_out B-frags

  const int tid  = threadIdx.x;
  const int lane = tid & 63;
  const int w    = tid >> 6;
  const int quad = lane >> 4;
  const int l16  = lane & 15;
  const int j    = 16 * w + l16;
  const int rowg0 = blockIdx.x * 32;
  const int mm   = tid & 15;
  const int xr   = tid >> 4;

  // ---- staging ----
  {
    uint4 z; z.x = z.y = z.z = z.w = 0u;
    uint4* a0p = (uint4*)A0;                  // 1280 uint4
    uint4* a1p = (uint4*)A1;                  // 1024 uint4
    for (int i = tid; i < 1280; i += 256) a0p[i] = z;
    for (int i = tid; i < 1024; i += 256) a1p[i] = z;
    if (tid < 128) ((uint4*)sWoutF)[tid] = ((const uint4*)pw)[256 * 64 + tid];
    if (tid < 128) xsrc[0][tid] = src[(long)(rowg0 + (tid >> 2)) * 256 + (tid & 3)];
  }
  const float4 wv = *(const float4*)&W_in[mm * 4];
  const float  bin = b_in[mm];

  bf16x8 B0[5][4], B1[4][4];
  float bias0[4], bias1[4];
  float c0[8] = {0,0,0,0,0,0,0,0}, c1[8] = {0,0,0,0,0,0,0,0};
  load_frags<3>(pw, 0, 48, w, lane, B0, B1);
#pragma unroll
  for (int g = 0; g < 4; g++){
    int n = 64*g + j;
    float s = (g == 2) ? -2.88539008f : -1.44269504f;
    bias0[g] = eb0[n] * s; bias1[g] = eb1[n] * s;
  }
  __syncthreads();

  unsigned short h0r[8], h1r[8];
  const int xoff = (xr | ((mm >> 3) << 4)) * 8 + (mm & 7);   // A-layout slot for k=mm

  // ================= encoder: 1 barrier/step (cell1 skewed by 1) =================
  for (int t = 0; t < 64; t++){
    int cur = t & 1, nxt = cur ^ 1;
    float xv;
    if (tid < 128)
      xv = src[(long)(rowg0 + (tid >> 2)) * 256 + ((t == 63 ? 63 : t + 1) << 2) + (tid & 3)];
    { // x-projection for rows xr, xr+16
      float4 x0 = *(const float4*)&xsrc[cur][xr * 4];
      float4 x1 = *(const float4*)&xsrc[cur][(xr + 16) * 4];
      float m0 = bin + x0.x*wv.x + x0.y*wv.y + x0.z*wv.z + x0.w*wv.w;
      float m1 = bin + x1.x*wv.x + x1.y*wv.y + x1.z*wv.z + x1.w*wv.w;
      A0[cur][0][xoff] = f2bf(m0);
      A0[cur][1][xoff] = f2bf(m1);
    }
    if (tid < 128) xsrc[nxt][tid] = xv;
    __syncthreads();
    // cell0(t)
    cell_compute<3, 2560>(&A0[cur][0][0], B0, bias0, c0, h0r, lane);
#pragma unroll
    for (int rt = 0; rt < 2; rt++){
      write_h(&A0[nxt][rt][0], 32 + j, quad, h0r + rt * 4);   // recurrent h0
      write_h(&A1[cur][rt][0],      j, quad, h0r + rt * 4);   // feed layer 1
    }
    // cell1(t-1)
    if (t > 0){
      cell_compute<4, 2048>(&A1[nxt][0][0], B1, bias1, c1, h1r, lane);
#pragma unroll
      for (int rt = 0; rt < 2; rt++)
        write_h(&A1[cur][rt][0], 64 + j, quad, h1r + rt * 4); // recurrent h1
    }
  }
  __syncthreads();
  // flush cell1(63): reads A1[1], writes recurrent into A1[0] for decoder t=0
  cell_compute<4, 2048>(&A1[1][0][0], B1, bias1, c1, h1r, lane);
#pragma unroll
  for (int rt = 0; rt < 2; rt++)
    write_h(&A1[0][rt][0], 64 + j, quad, h1r + rt * 4);

  // ================= decoder (2 barriers/step, folded feedback) =================
  load_frags<5>(pw, 112, 192, w, lane, B0, B1);
#pragma unroll
  for (int g = 0; g < 4; g++){
    int n = 64*g + j;
    float s = (g == 2) ? -2.88539008f : -1.44269504f;
    bias0[g] = db0[n] * s; bias1[g] = db1[n] * s;
  }
  const float4 bt4 = *(const float4*)bout;
  const float  cb  = bin + wv.x*bt4.x + wv.y*bt4.y + wv.z*bt4.z + wv.w*bt4.w;
  const float  bo  = (w < 2 && l16 < 4) ? bout[l16] : 0.0f;
  { // mtrg(0) = trg(:,0) @ W_in^T + b_in   (no bout term, no h1 fold at t=0)
    float4 x0 = *(const float4*)&trg[(long)(rowg0 + xr) * 256];
    float4 x1 = *(const float4*)&trg[(long)(rowg0 + xr + 16) * 256];
    float m0 = bin + x0.x*wv.x + x0.y*wv.y + x0.z*wv.z + x0.w*wv.w;
    float m1 = bin + x1.x*wv.x + x1.y*wv.y + x1.z*wv.z + x1.w*wv.w;
    A0[0][0][xoff] = f2bf(m0);
    A0[0][1][xoff] = f2bf(m1);
  }
  // note: A0 kt3,4 (h1 fold region) are still zero from init => correct t=0
  __syncthreads();

  for (int t = 0; t < 64; t++){
    int cur = t & 1, nxt = cur ^ 1;
    { // mtrg(t+1) = trg(:,t) @ W_in^T + (b_in + bout @ W_in^T)  -> A0[nxt]
      float4 x0 = *(const float4*)&trg[(long)(rowg0 + xr) * 256 + t * 4];
      float4 x1 = *(const float4*)&trg[(long)(rowg0 + xr + 16) * 256 + t * 4];
      float m0 = cb + x0.x*wv.x + x0.y*wv.y + x0.z*wv.z + x0.w*wv.w;
      float m1 = cb + x1.x*wv.x + x1.y*wv.y + x1.z*wv.z + x1.w*wv.w;
      A0[nxt][0][xoff] = f2bf(m0);
      A0[nxt][1][xoff] = f2bf(m1);
    }
    // skewed output projection: out(t-1) from h1(t-1) in A0[cur] kt3,4
    if (w < 2 && t > 0){
      const unsigned short* Ah = &A0[cur][w][0];
      bf16x8 a3  = *(const bf16x8*)(Ah + (3 * 64 + lane) * 8);
      bf16x8 a4  = *(const bf16x8*)(Ah + (4 * 64 + lane) * 8);
      bf16x8 bw0 = *(const bf16x8*)(sWoutF + lane * 8);
      bf16x8 bw1 = *(const bf16x8*)(sWoutF + 512 + lane * 8);
      f32x4 po = {bo, bo, bo, bo};
      po = __builtin_amdgcn_mfma_f32_16x16x32_bf16(a3, bw0, po, 0, 0, 0);
      po = __builtin_amdgcn_mfma_f32_16x16x32_bf16(a4, bw1, po, 0, 0, 0);
      if (l16 < 4){
#pragma unroll
        for (int e = 0; e < 4; e++){
          long idx = (long)(rowg0 + w * 16 + quad * 4 + e) * 256 + (t - 1) * 4 + l16;
          out[idx] = po[e] + trg[idx];
        }
      }
    }
    // cell0: K=160 = [mtrg | pad | h0 | h1-fold]
    cell_compute<5, 2560>(&A0[cur][0][0], B0, bias0, c0, h0r, lane);
#pragma unroll
    for (int rt = 0; rt < 2; rt++){
      write_h(&A0[nxt][rt][0], 32 + j, quad, h0r + rt * 4);
      write_h(&A1[cur][rt][0],      j, quad, h0r + rt * 4);
    }
    __syncthreads();                       // barB: h0 visible
    cell_compute<4, 2048>(&A1[cur][0][0], B1, bias1, c1, h1r, lane);
#pragma unroll
    for (int rt = 0; rt < 2; rt++){
      write_h(&A1[nxt][rt][0], 64 + j, quad, h1r + rt * 4);   // recurrent h1
      write_h(&A0[nxt][rt][0], 96 + j, quad, h1r + rt * 4);   // feedback fold region
    }
    __syncthreads();                       // barA': h1/mtrg visible for next step
  }
  // final output column t=63: h1(63) sits in A0[0] kt3,4
  if (w < 2){
    const unsigned short* Ah = &A0[0][w][0];
    bf16x8 a3  = *(const bf16x8*)(Ah + (3 * 64 + lane) * 8);
    bf16x8 a4  = *(const bf16x8*)(Ah + (4 * 64 + lane) * 8);
    bf16x8 bw0 = *(const bf16x8*)(sWoutF + lane * 8);
    bf16x8 bw1 = *(const bf16x8*)(sWoutF + 512 + lane * 8);
    f32x4 po = {bo, bo, bo, bo};
    po = __builtin_amdgcn_mfma_f32_16x16x32_bf16(a3, bw0, po, 0, 0, 0);
    po = __builtin_amdgcn_mfma_f32_16x16x32_bf16(a4, bw1, po, 0, 0, 0);
    if (l16 < 4){
#pragma unroll
      for (int e = 0; e < 4; e++){
        long idx = (long)(rowg0 + w * 16 + quad * 4 + e) * 256 + 63 * 4 + l16;
        out[idx] = po[e] + trg[idx];
      }
    }
  }
}

extern "C" void kernel_launch(void* const* d_in, const int* in_sizes, int n_in,
                              void* d_out, int out_size, void* d_ws, size_t ws_size,
                              hipStream_t stream){
  (void)n_in; (void)out_size; (void)ws_size;
  const float* src   = (const float*)d_in[0];
  const float* trg   = (const float*)d_in[1];
  const float* W_in  = (const float*)d_in[2];
  const float* b_in  = (const float*)d_in[3];
  const float* eWih0 = (const float*)d_in[4];
  const float* eWhh0 = (const float*)d_in[5];
  const float* eb0   = (const float*)d_in[6];
  const float* eWih1 = (const float*)d_in[7];
  const float* eWhh1 = (const float*)d_in[8];
  const float* eb1   = (const float*)d_in[9];
  const float* dWih0 = (const float*)d_in[10];
  const float* dWhh0 = (const float*)d_in[11];
  const float* db0   = (const float*)d_in[12];
  const float* dWih1 = (const float*)d_in[13];
  const float* dWhh1 = (const float*)d_in[14];
  const float* db1   = (const float*)d_in[15];
  const float* Wout  = (const float*)d_in[16];
  const float* bout  = (const float*)d_in[17];
  unsigned short* pw = (unsigned short*)d_ws;          // needs 264,192 bytes

  pack_weights<<<65, 256, 0, stream>>>(eWih0, eWhh0, eWih1, eWhh1,
                                       dWih0, dWhh0, dWih1, dWhh1, Wout, W_in, pw);

  int B    = in_sizes[0] / 256;                        // S*I = 256
  int nblk = B / 32;
  lstm_main<<<nblk, 256, 0, stream>>>(src, trg, W_in, b_in, eb0, eb1, db0, db1,
                                      bout, pw, (float*)d_out);
}

// Round 4
// 479.965 us; speedup vs baseline: 3.4641x; 1.0500x over previous
//
#include <hip/hip_runtime.h>

typedef __bf16 bf16x8 __attribute__((ext_vector_type(8)));
typedef float  f32x4  __attribute__((ext_vector_type(4)));

__device__ __forceinline__ unsigned short f2bf(float x){
  return __builtin_bit_cast(unsigned short, (__bf16)x);   // HW v_cvt on gfx950, RNE
}

// ---------------------------------------------------------------------------
// Weight pack: MFMA B-fragment order (bf16), lane holds B[k=kt*32+(lane>>4)*8+jj][n=lane&15].
// Gate weights PRE-SCALED by -log2(e) (i,f,o) or -2*log2(e) (g) so the MFMA
// accumulator is directly the exp2() argument.
// Sections: [0,48)    encL0 (ntile*3+kt, K: x 0..16|pad|h 32..96)
//           [48,112)  encL1 (ntile*4+kt, K: h0 0..64|h1 64..128)
//           [112,192) decL0 (ntile*5+kt, K: m 0..16|pad|h0 32..96|h1-fold 96..160)
//                     kt 3,4 hold Wx1 = dWih0 @ W_in @ W_out  (feedback fold)
//           [192,256) decL1 (ntile*4+kt)
//           [256,258) W_out (N=4 padded to 16, K=64), unscaled
// ---------------------------------------------------------------------------
__global__ void pack_weights(const float* __restrict__ eWih0, const float* __restrict__ eWhh0,
                             const float* __restrict__ eWih1, const float* __restrict__ eWhh1,
                             const float* __restrict__ dWih0, const float* __restrict__ dWhh0,
                             const float* __restrict__ dWih1, const float* __restrict__ dWhh1,
                             const float* __restrict__ Wout,  const float* __restrict__ W_in,
                             unsigned short* __restrict__ out){
  int t = blockIdx.x * 256 + threadIdx.x;
  if (t >= 258 * 64) return;
  int lane = t & 63;
  int f    = t >> 6;
  unsigned short vals[8];
  if (f >= 256){                                       // W_out frags (NOT scaled)
    int kt = f - 256, n = lane & 15;
#pragma unroll
    for (int jj = 0; jj < 8; jj++){
      int k = kt * 32 + (lane >> 4) * 8 + jj;
      vals[jj] = (n < 4) ? f2bf(Wout[n * 64 + k]) : (unsigned short)0;
    }
  } else {
    const float *Wih, *Whh; int kx, ntile, kt, nkt;
    if (f < 48)       { Wih=eWih0; Whh=eWhh0; kx=16; nkt=3; ntile=f/3;        kt=f%3; }
    else if (f < 112) { Wih=eWih1; Whh=eWhh1; kx=64; nkt=4; ntile=(f-48)/4;   kt=(f-48)%4; }
    else if (f < 192) { Wih=dWih0; Whh=dWhh0; kx=16; nkt=5; ntile=(f-112)/5;  kt=(f-112)%5; }
    else              { Wih=dWih1; Whh=dWhh1; kx=64; nkt=4; ntile=(f-192)/4;  kt=(f-192)%4; }
    int n    = ntile * 16 + (lane & 15);
    int hoff = (kx == 16) ? 32 : 64;
    // gate index = ntile/4; gates i,f,o get -log2(e), gate g gets -2*log2(e)
    float scale = ((ntile >> 2) == 2) ? -2.88539008f : -1.44269504f;
#pragma unroll
    for (int jj = 0; jj < 8; jj++){
      int k = kt * 32 + (lane >> 4) * 8 + jj;
      float v;
      if (nkt == 5 && k >= 96){
        // folded feedback weights: Wx1[n][c] = sum_m Wih0[n][m] * (W_in @ W_out)[m][c]
        int c = k - 96;
        float acc = 0.0f;
        for (int m = 0; m < 16; m++){
          float wf = 0.0f;
          for (int i = 0; i < 4; i++) wf += W_in[m * 4 + i] * Wout[i * 64 + c];
          acc += Wih[n * 16 + m] * wf;
        }
        v = acc;
      }
      else if (k < kx)   v = Wih[n * kx + k];
      else if (k < hoff) v = 0.0f;
      else               v = Whh[n * 64 + (k - hoff)];
      vals[jj] = f2bf(v * scale);
    }
  }
  uint4 o;
  o.x = (unsigned)vals[0] | ((unsigned)vals[1] << 16);
  o.y = (unsigned)vals[2] | ((unsigned)vals[3] << 16);
  o.z = (unsigned)vals[4] | ((unsigned)vals[5] << 16);
  o.w = (unsigned)vals[6] | ((unsigned)vals[7] << 16);
  ((uint4*)out)[f * 64 + lane] = o;
}

// A-layout (per 16-row subtile): elem(m,k) at ((k>>5)*64 + (m | (((k>>3)&3)<<4)))*8 + (k&7)
__device__ __forceinline__ void write_h(unsigned short* buf, int k, int quad,
                                        const unsigned short* h){
  unsigned short* p = buf + (((k >> 5) * 64) + quad * 4 + (((k >> 3) & 3) << 4)) * 8 + (k & 7);
#pragma unroll
  for (int e = 0; e < 4; e++) p[e * 8] = h[e];
}

// load LOAD0 of STRIDE0 K-tiles for L0 (rest streamed from LDS), all 4 for L1
template<int STRIDE0, int LOAD0>
__device__ __forceinline__ void load_frags(const unsigned short* __restrict__ pw,
                                           int base0, int base1, int w, int lane,
                                           bf16x8 (&B0)[4][4], bf16x8 (&B1)[4][4]){
#pragma unroll
  for (int g = 0; g < 4; g++){
    int nt = 4 * g + w;
#pragma unroll
    for (int kt = 0; kt < LOAD0; kt++)
      B0[kt][g] = *(const bf16x8*)(pw + (((long)(base0 + nt * STRIDE0 + kt)) * 64 + lane) * 8);
#pragma unroll
    for (int kt = 0; kt < 4; kt++)
      B1[kt][g] = *(const bf16x8*)(pw + (((long)(base1 + nt * 4 + kt)) * 64 + lane) * 8);
  }
}

// One LSTM cell step for ONE 16-row subtile, this wave's 16 j's.
// acc arrives exp2-ready (pre-scaled weights). Fused reciprocals:
//   sig(i)*tanh(g) = (1-eg)/((1+ei)(1+eg)),  sig(o)*tanh(c) = (ec-1)/((1+eo)(1+ec))
// c kept pre-scaled by 2*log2(e). FOLD: extra K-tile (index KT) with B streamed
// from LDS (sFold) — the decoder h1-feedback fold.
template<int KT, bool FOLD>
__device__ __forceinline__ void cell_rt(const unsigned short* __restrict__ A,
                                        const bf16x8 (*B)[4],
                                        const unsigned short* __restrict__ sFold,
                                        const float (&bias)[4],
                                        float* __restrict__ c,
                                        unsigned short* __restrict__ hout,
                                        int lane, int w){
  f32x4 acc[4];
#pragma unroll
  for (int g = 0; g < 4; g++){
    f32x4 b = {bias[g], bias[g], bias[g], bias[g]};
    acc[g] = b;
  }
#pragma unroll
  for (int kt = 0; kt < KT; kt++){
    bf16x8 a = *(const bf16x8*)(A + (kt * 64 + lane) * 8);
#pragma unroll
    for (int g = 0; g < 4; g++)
      acc[g] = __builtin_amdgcn_mfma_f32_16x16x32_bf16(a, B[kt][g], acc[g], 0, 0, 0);
  }
  if constexpr (FOLD){
    bf16x8 a = *(const bf16x8*)(A + (KT * 64 + lane) * 8);
#pragma unroll
    for (int g = 0; g < 4; g++){
      bf16x8 b = *(const bf16x8*)(sFold + (((4 * g + w) * 64) + lane) * 8);
      acc[g] = __builtin_amdgcn_mfma_f32_16x16x32_bf16(a, b, acc[g], 0, 0, 0);
    }
  }
#pragma unroll
  for (int e = 0; e < 4; e++){
    float ei = __builtin_amdgcn_exp2f(acc[0][e]);
    float ef = __builtin_amdgcn_exp2f(acc[1][e]);
    float eg = __builtin_amdgcn_exp2f(acc[2][e]);
    float eo = __builtin_amdgcn_exp2f(acc[3][e]);
    float rf  = __builtin_amdgcn_rcpf(1.0f + ef);
    float rig = __builtin_amdgcn_rcpf((1.0f + ei) * (1.0f + eg));
    float c2  = fmaf(c[e], rf, fmaf(-2.88539008f, eg, 2.88539008f) * rig);
    c[e] = c2;
    float ec  = __builtin_amdgcn_exp2f(c2);
    float rot = __builtin_amdgcn_rcpf((1.0f + eo) * (1.0f + ec));
    hout[e] = f2bf((ec - 1.0f) * rot);
  }
}

// ---------------------------------------------------------------------------
// Main: one block = 32 batch rows (grid 512 = 2 blocks/CU, all resident).
// Encoder: 1 barrier/step (layer-skewed). Decoder: 2 barriers/step via the
// Wx1 feedback fold (kt4 B-frags streamed from LDS to stay under the 256-reg
// cap); W_out projection runs SKEWED (out(t-1) during step t).
// ---------------------------------------------------------------------------
__global__ __launch_bounds__(256, 2)
void lstm_main(const float* __restrict__ src, const float* __restrict__ trg,
               const float* __restrict__ W_in, const float* __restrict__ b_in,
               const float* __restrict__ eb0, const float* __restrict__ eb1,
               const float* __restrict__ db0, const float* __restrict__ db1,
               const float* __restrict__ bout,
               const unsigned short* __restrict__ pw,
               float* __restrict__ out){
  __shared__ __align__(16) unsigned short A0[2][2][2560];   // ping-pong, 2 subtiles, K=160
  __shared__ __align__(16) unsigned short A1[2][2][2048];   // K=128
  __shared__ __align__(16) float xsrc[2][128];              // encoder x ping-pong
  __shared__ __align__(16) unsigned short sWoutF[1024];     // W_out B-frags (2 KB)
  __shared__ __align__(16) unsigned short sFold[8192];      // decL0 kt4 B-frags (16 KB)

  const int tid  = threadIdx.x;
  const int lane = tid & 63;
  const int w    = tid >> 6;
  const int quad = lane >> 4;
  const int l16  = lane & 15;
  const int j    = 16 * w + l16;
  const int rowg0 = blockIdx.x * 32;
  const int mm   = tid & 15;
  const int xr   = tid >> 4;

  // ---- staging ----
  {
    uint4 z; z.x = z.y = z.z = z.w = 0u;
    uint4* a0p = (uint4*)A0;                  // 1280 uint4
    uint4* a1p = (uint4*)A1;                  // 1024 uint4
    for (int i = tid; i < 1280; i += 256) a0p[i] = z;
    for (int i = tid; i < 1024; i += 256) a1p[i] = z;
    if (tid < 128) ((uint4*)sWoutF)[tid] = ((const uint4*)pw)[256 * 64 + tid];
    // decL0 kt4 fold frags: f = 112 + nt*5 + 4, nt = 0..15  (1024 uint4)
    for (int i = tid; i < 1024; i += 256)
      ((uint4*)sFold)[i] = ((const uint4*)pw)[(112 + (i >> 6) * 5 + 4) * 64 + (i & 63)];
    if (tid < 128) xsrc[0][tid] = src[(long)(rowg0 + (tid >> 2)) * 256 + (tid & 3)];
  }
  const float4 wv = *(const float4*)&W_in[mm * 4];
  const float  bin = b_in[mm];

  bf16x8 B0[4][4], B1[4][4];
  float bias0[4], bias1[4];
  float c0[8] = {0,0,0,0,0,0,0,0}, c1[8] = {0,0,0,0,0,0,0,0};
  load_frags<3, 3>(pw, 0, 48, w, lane, B0, B1);
#pragma unroll
  for (int g = 0; g < 4; g++){
    int n = 64*g + j;
    float s = (g == 2) ? -2.88539008f : -1.44269504f;
    bias0[g] = eb0[n] * s; bias1[g] = eb1[n] * s;
  }
  __syncthreads();

  unsigned short h0r[8], h1r[8];
  const int xoff = (xr | ((mm >> 3) << 4)) * 8 + (mm & 7);   // A-layout slot for k=mm

  // ================= encoder: 1 barrier/step (cell1 skewed by 1) =================
  for (int t = 0; t < 64; t++){
    int cur = t & 1, nxt = cur ^ 1;
    float xv;
    if (tid < 128)
      xv = src[(long)(rowg0 + (tid >> 2)) * 256 + ((t == 63 ? 63 : t + 1) << 2) + (tid & 3)];
    { // x-projection for rows xr, xr+16
      float4 x0 = *(const float4*)&xsrc[cur][xr * 4];
      float4 x1 = *(const float4*)&xsrc[cur][(xr + 16) * 4];
      float m0 = bin + x0.x*wv.x + x0.y*wv.y + x0.z*wv.z + x0.w*wv.w;
      float m1 = bin + x1.x*wv.x + x1.y*wv.y + x1.z*wv.z + x1.w*wv.w;
      A0[cur][0][xoff] = f2bf(m0);
      A0[cur][1][xoff] = f2bf(m1);
    }
    if (tid < 128) xsrc[nxt][tid] = xv;
    __syncthreads();
    // cell0(t)
    cell_rt<3, false>(&A0[cur][0][0], B0, nullptr, bias0, c0,     h0r,     lane, w);
    cell_rt<3, false>(&A0[cur][1][0], B0, nullptr, bias0, c0 + 4, h0r + 4, lane, w);
#pragma unroll
    for (int rt = 0; rt < 2; rt++){
      write_h(&A0[nxt][rt][0], 32 + j, quad, h0r + rt * 4);   // recurrent h0
      write_h(&A1[cur][rt][0],      j, quad, h0r + rt * 4);   // feed layer 1
    }
    // cell1(t-1)
    if (t > 0){
      cell_rt<4, false>(&A1[nxt][0][0], B1, nullptr, bias1, c1,     h1r,     lane, w);
      cell_rt<4, false>(&A1[nxt][1][0], B1, nullptr, bias1, c1 + 4, h1r + 4, lane, w);
#pragma unroll
      for (int rt = 0; rt < 2; rt++)
        write_h(&A1[cur][rt][0], 64 + j, quad, h1r + rt * 4); // recurrent h1
    }
  }
  __syncthreads();
  // flush cell1(63): reads A1[1], writes recurrent into A1[0] for decoder t=0
  cell_rt<4, false>(&A1[1][0][0], B1, nullptr, bias1, c1,     h1r,     lane, w);
  cell_rt<4, false>(&A1[1][1][0], B1, nullptr, bias1, c1 + 4, h1r + 4, lane, w);
#pragma unroll
  for (int rt = 0; rt < 2; rt++)
    write_h(&A1[0][rt][0], 64 + j, quad, h1r + rt * 4);

  // ================= decoder (2 barriers/step, folded feedback) =================
  load_frags<5, 4>(pw, 112, 192, w, lane, B0, B1);
#pragma unroll
  for (int g = 0; g < 4; g++){
    int n = 64*g + j;
    float s = (g == 2) ? -2.88539008f : -1.44269504f;
    bias0[g] = db0[n] * s; bias1[g] = db1[n] * s;
  }
  const float4 bt4 = *(const float4*)bout;
  const float  cb  = bin + wv.x*bt4.x + wv.y*bt4.y + wv.z*bt4.z + wv.w*bt4.w;
  const float  bo  = (w < 2 && l16 < 4) ? bout[l16] : 0.0f;
  { // mtrg(0) = trg(:,0) @ W_in^T + b_in   (no bout term, no h1 fold at t=0)
    float4 x0 = *(const float4*)&trg[(long)(rowg0 + xr) * 256];
    float4 x1 = *(const float4*)&trg[(long)(rowg0 + xr + 16) * 256];
    float m0 = bin + x0.x*wv.x + x0.y*wv.y + x0.z*wv.z + x0.w*wv.w;
    float m1 = bin + x1.x*wv.x + x1.y*wv.y + x1.z*wv.z + x1.w*wv.w;
    A0[0][0][xoff] = f2bf(m0);
    A0[0][1][xoff] = f2bf(m1);
  }
  // note: A0 kt3,4 (h1 fold region) are still zero from init => correct t=0
  __syncthreads();

  for (int t = 0; t < 64; t++){
    int cur = t & 1, nxt = cur ^ 1;
    { // mtrg(t+1) = trg(:,t) @ W_in^T + (b_in + bout @ W_in^T)  -> A0[nxt]
      float4 x0 = *(const float4*)&trg[(long)(rowg0 + xr) * 256 + t * 4];
      float4 x1 = *(const float4*)&trg[(long)(rowg0 + xr + 16) * 256 + t * 4];
      float m0 = cb + x0.x*wv.x + x0.y*wv.y + x0.z*wv.z + x0.w*wv.w;
      float m1 = cb + x1.x*wv.x + x1.y*wv.y + x1.z*wv.z + x1.w*wv.w;
      A0[nxt][0][xoff] = f2bf(m0);
      A0[nxt][1][xoff] = f2bf(m1);
    }
    // skewed output projection: out(t-1) from h1(t-1) in A0[cur] kt3,4
    if (w < 2 && t > 0){
      const unsigned short* Ah = &A0[cur][w][0];
      bf16x8 a3  = *(const bf16x8*)(Ah + (3 * 64 + lane) * 8);
      bf16x8 a4  = *(const bf16x8*)(Ah + (4 * 64 + lane) * 8);
      bf16x8 bw0 = *(const bf16x8*)(sWoutF + lane * 8);
      bf16x8 bw1 = *(const bf16x8*)(sWoutF + 512 + lane * 8);
      f32x4 po = {bo, bo, bo, bo};
      po = __builtin_amdgcn_mfma_f32_16x16x32_bf16(a3, bw0, po, 0, 0, 0);
      po = __builtin_amdgcn_mfma_f32_16x16x32_bf16(a4, bw1, po, 0, 0, 0);
      if (l16 < 4){
#pragma unroll
        for (int e = 0; e < 4; e++){
          long idx = (long)(rowg0 + w * 16 + quad * 4 + e) * 256 + (t - 1) * 4 + l16;
          out[idx] = po[e] + trg[idx];
        }
      }
    }
    // cell0: K=160 = [mtrg | pad | h0 | h1-fold(LDS-streamed B)]
    cell_rt<4, true>(&A0[cur][0][0], B0, sFold, bias0, c0,     h0r,     lane, w);
    cell_rt<4, true>(&A0[cur][1][0], B0, sFold, bias0, c0 + 4, h0r + 4, lane, w);
#pragma unroll
    for (int rt = 0; rt < 2; rt++){
      write_h(&A0[nxt][rt][0], 32 + j, quad, h0r + rt * 4);
      write_h(&A1[cur][rt][0],      j, quad, h0r + rt * 4);
    }
    __syncthreads();                       // barB: h0 visible
    cell_rt<4, false>(&A1[cur][0][0], B1, nullptr, bias1, c1,     h1r,     lane, w);
    cell_rt<4, false>(&A1[cur][1][0], B1, nullptr, bias1, c1 + 4, h1r + 4, lane, w);
#pragma unroll
    for (int rt = 0; rt < 2; rt++){
      write_h(&A1[nxt][rt][0], 64 + j, quad, h1r + rt * 4);   // recurrent h1
      write_h(&A0[nxt][rt][0], 96 + j, quad, h1r + rt * 4);   // feedback fold region
    }
    __syncthreads();                       // barA': h1/mtrg visible for next step
  }
  // final output column t=63: h1(63) sits in A0[0] kt3,4
  if (w < 2){
    const unsigned short* Ah = &A0[0][w][0];
    bf16x8 a3  = *(const bf16x8*)(Ah + (3 * 64 + lane) * 8);
    bf16x8 a4  = *(const bf16x8*)(Ah + (4 * 64 + lane) * 8);
    bf16x8 bw0 = *(const bf16x8*)(sWoutF + lane * 8);
    bf16x8 bw1 = *(const bf16x8*)(sWoutF + 512 + lane * 8);
    f32x4 po = {bo, bo, bo, bo};
    po = __builtin_amdgcn_mfma_f32_16x16x32_bf16(a3, bw0, po, 0, 0, 0);
    po = __builtin_amdgcn_mfma_f32_16x16x32_bf16(a4, bw1, po, 0, 0, 0);
    if (l16 < 4){
#pragma unroll
      for (int e = 0; e < 4; e++){
        long idx = (long)(rowg0 + w * 16 + quad * 4 + e) * 256 + 63 * 4 + l16;
        out[idx] = po[e] + trg[idx];
      }
    }
  }
}

extern "C" void kernel_launch(void* const* d_in, const int* in_sizes, int n_in,
                              void* d_out, int out_size, void* d_ws, size_t ws_size,
                              hipStream_t stream){
  (void)n_in; (void)out_size; (void)ws_size;
  const float* src   = (const float*)d_in[0];
  const float* trg   = (const float*)d_in[1];
  const float* W_in  = (const float*)d_in[2];
  const float* b_in  = (const float*)d_in[3];
  const float* eWih0 = (const float*)d_in[4];
  const float* eWhh0 = (const float*)d_in[5];
  const float* eb0   = (const float*)d_in[6];
  const float* eWih1 = (const float*)d_in[7];
  const float* eWhh1 = (const float*)d_in[8];
  const float* eb1   = (const float*)d_in[9];
  const float* dWih0 = (const float*)d_in[10];
  const float* dWhh0 = (const float*)d_in[11];
  const float* db0   = (const float*)d_in[12];
  const float* dWih1 = (const float*)d_in[13];
  const float* dWhh1 = (const float*)d_in[14];
  const float* db1   = (const float*)d_in[15];
  const float* Wout  = (const float*)d_in[16];
  const float* bout  = (const float*)d_in[17];
  unsigned short* pw = (unsigned short*)d_ws;          // needs 264,192 bytes

  pack_weights<<<65, 256, 0, stream>>>(eWih0, eWhh0, eWih1, eWhh1,
                                       dWih0, dWhh0, dWih1, dWhh1, Wout, W_in, pw);

  int B    = in_sizes[0] / 256;                        // S*I = 256
  int nblk = B / 32;
  lstm_main<<<nblk, 256, 0, stream>>>(src, trg, W_in, b_in, eb0, eb1, db0, db1,
                                      bout, pw, (float*)d_out);
}

// Round 5
// 473.717 us; speedup vs baseline: 3.5098x; 1.0132x over previous
//
#include <hip/hip_runtime.h>

typedef __bf16 bf16x8 __attribute__((ext_vector_type(8)));
typedef float  f32x4  __attribute__((ext_vector_type(4)));

__device__ __forceinline__ unsigned short f2bf(float x){
  return __builtin_bit_cast(unsigned short, (__bf16)x);   // HW v_cvt on gfx950, RNE
}

// ---------------------------------------------------------------------------
// Weight pack: MFMA B-fragment order (bf16), lane holds B[k=kt*32+(lane>>4)*8+jj][n=lane&15].
// Gate weights PRE-SCALED by -log2(e) (i,f,o) or -2*log2(e) (g) so the MFMA
// accumulator is directly the exp2() argument.
// Sections: [0,48)    encL0 (ntile*3+kt, K: x 0..16|pad|h 32..96)
//           [48,112)  encL1 (ntile*4+kt, K: h0 0..64|h1 64..128)
//           [112,192) decL0 (ntile*5+kt, K: m 0..16|pad|h0 32..96|h1-fold 96..160)
//                     kt 3,4 hold Wx1 = dWih0 @ W_in @ W_out  (feedback fold)
//           [192,256) decL1 (ntile*4+kt)
//           [256,258) W_out (N=4 padded to 16, K=64), unscaled
// ---------------------------------------------------------------------------
__global__ void pack_weights(const float* __restrict__ eWih0, const float* __restrict__ eWhh0,
                             const float* __restrict__ eWih1, const float* __restrict__ eWhh1,
                             const float* __restrict__ dWih0, const float* __restrict__ dWhh0,
                             const float* __restrict__ dWih1, const float* __restrict__ dWhh1,
                             const float* __restrict__ Wout,  const float* __restrict__ W_in,
                             unsigned short* __restrict__ out){
  int t = blockIdx.x * 256 + threadIdx.x;
  if (t >= 258 * 64) return;
  int lane = t & 63;
  int f    = t >> 6;
  unsigned short vals[8];
  if (f >= 256){                                       // W_out frags (NOT scaled)
    int kt = f - 256, n = lane & 15;
#pragma unroll
    for (int jj = 0; jj < 8; jj++){
      int k = kt * 32 + (lane >> 4) * 8 + jj;
      vals[jj] = (n < 4) ? f2bf(Wout[n * 64 + k]) : (unsigned short)0;
    }
  } else {
    const float *Wih, *Whh; int kx, ntile, kt, nkt;
    if (f < 48)       { Wih=eWih0; Whh=eWhh0; kx=16; nkt=3; ntile=f/3;        kt=f%3; }
    else if (f < 112) { Wih=eWih1; Whh=eWhh1; kx=64; nkt=4; ntile=(f-48)/4;   kt=(f-48)%4; }
    else if (f < 192) { Wih=dWih0; Whh=dWhh0; kx=16; nkt=5; ntile=(f-112)/5;  kt=(f-112)%5; }
    else              { Wih=dWih1; Whh=dWhh1; kx=64; nkt=4; ntile=(f-192)/4;  kt=(f-192)%4; }
    int n    = ntile * 16 + (lane & 15);
    int hoff = (kx == 16) ? 32 : 64;
    // gate index = ntile/4; gates i,f,o get -log2(e), gate g gets -2*log2(e)
    float scale = ((ntile >> 2) == 2) ? -2.88539008f : -1.44269504f;
#pragma unroll
    for (int jj = 0; jj < 8; jj++){
      int k = kt * 32 + (lane >> 4) * 8 + jj;
      float v;
      if (nkt == 5 && k >= 96){
        // folded feedback weights: Wx1[n][c] = sum_m Wih0[n][m] * (W_in @ W_out)[m][c]
        int c = k - 96;
        float acc = 0.0f;
        for (int m = 0; m < 16; m++){
          float wf = 0.0f;
          for (int i = 0; i < 4; i++) wf += W_in[m * 4 + i] * Wout[i * 64 + c];
          acc += Wih[n * 16 + m] * wf;
        }
        v = acc;
      }
      else if (k < kx)   v = Wih[n * kx + k];
      else if (k < hoff) v = 0.0f;
      else               v = Whh[n * 64 + (k - hoff)];
      vals[jj] = f2bf(v * scale);
    }
  }
  uint4 o;
  o.x = (unsigned)vals[0] | ((unsigned)vals[1] << 16);
  o.y = (unsigned)vals[2] | ((unsigned)vals[3] << 16);
  o.z = (unsigned)vals[4] | ((unsigned)vals[5] << 16);
  o.w = (unsigned)vals[6] | ((unsigned)vals[7] << 16);
  ((uint4*)out)[f * 64 + lane] = o;
}

// A-layout (per 16-row subtile): elem(m,k) at ((k>>5)*64 + (m | (((k>>3)&3)<<4)))*8 + (k&7)
__device__ __forceinline__ void write_h(unsigned short* buf, int k, int quad,
                                        const unsigned short* h){
  unsigned short* p = buf + (((k >> 5) * 64) + quad * 4 + (((k >> 3) & 3) << 4)) * 8 + (k & 7);
#pragma unroll
  for (int e = 0; e < 4; e++) p[e * 8] = h[e];
}

// load LOAD0 of STRIDE0 K-tiles for L0 (rest streamed from LDS), all 4 for L1
template<int STRIDE0, int LOAD0>
__device__ __forceinline__ void load_frags(const unsigned short* __restrict__ pw,
                                           int base0, int base1, int w, int lane,
                                           bf16x8 (&B0)[4][4], bf16x8 (&B1)[4][4]){
#pragma unroll
  for (int g = 0; g < 4; g++){
    int nt = 4 * g + w;
#pragma unroll
    for (int kt = 0; kt < LOAD0; kt++)
      B0[kt][g] = *(const bf16x8*)(pw + (((long)(base0 + nt * STRIDE0 + kt)) * 64 + lane) * 8);
#pragma unroll
    for (int kt = 0; kt < 4; kt++)
      B1[kt][g] = *(const bf16x8*)(pw + (((long)(base1 + nt * 4 + kt)) * 64 + lane) * 8);
  }
}

// One LSTM cell step for 32 rows (BOTH 16-row subtiles interleaved: 8 indep
// MFMA accumulator chains for latency cover), this wave's 16 j's.
// acc arrives exp2-ready (pre-scaled weights). Fused reciprocals:
//   sig(i)*tanh(g) = (1-eg)/((1+ei)(1+eg)),  sig(o)*tanh(c) = (ec-1)/((1+eo)(1+ec))
// c kept pre-scaled by 2*log2(e). FOLD: extra K-tile (index KT) with B streamed
// from LDS (sFold) — the decoder h1-feedback fold.
template<int KT, int SZ, bool FOLD>
__device__ __forceinline__ void cell_compute(const unsigned short* __restrict__ A,
                                             const bf16x8 (*B)[4],
                                             const unsigned short* __restrict__ sFold,
                                             const float (&bias)[4],
                                             float (&c)[8],
                                             unsigned short (&hout)[8],
                                             int lane, int w){
  f32x4 acc[4][2];
#pragma unroll
  for (int g = 0; g < 4; g++){
    f32x4 b = {bias[g], bias[g], bias[g], bias[g]};
    acc[g][0] = b; acc[g][1] = b;
  }
#pragma unroll
  for (int kt = 0; kt < KT; kt++){
    bf16x8 a0 = *(const bf16x8*)(A +      (kt * 64 + lane) * 8);
    bf16x8 a1 = *(const bf16x8*)(A + SZ + (kt * 64 + lane) * 8);
#pragma unroll
    for (int g = 0; g < 4; g++){
      acc[g][0] = __builtin_amdgcn_mfma_f32_16x16x32_bf16(a0, B[kt][g], acc[g][0], 0, 0, 0);
      acc[g][1] = __builtin_amdgcn_mfma_f32_16x16x32_bf16(a1, B[kt][g], acc[g][1], 0, 0, 0);
    }
  }
  if constexpr (FOLD){
    bf16x8 a0 = *(const bf16x8*)(A +      (KT * 64 + lane) * 8);
    bf16x8 a1 = *(const bf16x8*)(A + SZ + (KT * 64 + lane) * 8);
#pragma unroll
    for (int g = 0; g < 4; g++){
      bf16x8 b = *(const bf16x8*)(sFold + (((4 * g + w) * 64) + lane) * 8);
      acc[g][0] = __builtin_amdgcn_mfma_f32_16x16x32_bf16(a0, b, acc[g][0], 0, 0, 0);
      acc[g][1] = __builtin_amdgcn_mfma_f32_16x16x32_bf16(a1, b, acc[g][1], 0, 0, 0);
    }
  }
#pragma unroll
  for (int rt = 0; rt < 2; rt++){
#pragma unroll
    for (int e = 0; e < 4; e++){
      int idx = rt * 4 + e;
      float ei = __builtin_amdgcn_exp2f(acc[0][rt][e]);
      float ef = __builtin_amdgcn_exp2f(acc[1][rt][e]);
      float eg = __builtin_amdgcn_exp2f(acc[2][rt][e]);
      float eo = __builtin_amdgcn_exp2f(acc[3][rt][e]);
      float rf  = __builtin_amdgcn_rcpf(1.0f + ef);
      float rig = __builtin_amdgcn_rcpf((1.0f + ei) * (1.0f + eg));
      float c2  = fmaf(c[idx], rf, fmaf(-2.88539008f, eg, 2.88539008f) * rig);
      c[idx] = c2;
      float ec  = __builtin_amdgcn_exp2f(c2);
      float rot = __builtin_amdgcn_rcpf((1.0f + eo) * (1.0f + ec));
      hout[idx] = f2bf((ec - 1.0f) * rot);
    }
  }
}

// ---------------------------------------------------------------------------
// Main: one block = 32 batch rows (grid 512 = 2 blocks/CU, all resident).
// Encoder: 1 barrier/step (layer-skewed). Decoder: 2 barriers/step via the
// Wx1 feedback fold (kt4 B-frags streamed from LDS to stay under the 256-reg
// cap); W_out projection runs SKEWED (out(t-1) during step t).
// ---------------------------------------------------------------------------
__global__ __launch_bounds__(256, 2)
void lstm_main(const float* __restrict__ src, const float* __restrict__ trg,
               const float* __restrict__ W_in, const float* __restrict__ b_in,
               const float* __restrict__ eb0, const float* __restrict__ eb1,
               const float* __restrict__ db0, const float* __restrict__ db1,
               const float* __restrict__ bout,
               const unsigned short* __restrict__ pw,
               float* __restrict__ out){
  __shared__ __align__(16) unsigned short A0[2][2][2560];   // ping-pong, 2 subtiles, K=160
  __shared__ __align__(16) unsigned short A1[2][2][2048];   // K=128
  __shared__ __align__(16) float xsrc[2][128];              // encoder x ping-pong
  __shared__ __align__(16) unsigned short sWoutF[1024];     // W_out B-frags (2 KB)
  __shared__ __align__(16) unsigned short sFold[8192];      // decL0 kt4 B-frags (16 KB)

  const int tid  = threadIdx.x;
  const int lane = tid & 63;
  const int w    = tid >> 6;
  const int quad = lane >> 4;
  const int l16  = lane & 15;
  const int j    = 16 * w + l16;
  const int rowg0 = blockIdx.x * 32;
  const int mm   = tid & 15;
  const int xr   = tid >> 4;

  // ---- staging ----
  {
    uint4 z; z.x = z.y = z.z = z.w = 0u;
    uint4* a0p = (uint4*)A0;                  // 1280 uint4
    uint4* a1p = (uint4*)A1;                  // 1024 uint4
    for (int i = tid; i < 1280; i += 256) a0p[i] = z;
    for (int i = tid; i < 1024; i += 256) a1p[i] = z;
    if (tid < 128) ((uint4*)sWoutF)[tid] = ((const uint4*)pw)[256 * 64 + tid];
    // decL0 kt4 fold frags: f = 112 + nt*5 + 4, nt = 0..15  (1024 uint4)
    for (int i = tid; i < 1024; i += 256)
      ((uint4*)sFold)[i] = ((const uint4*)pw)[(112 + (i >> 6) * 5 + 4) * 64 + (i & 63)];
    if (tid < 128) xsrc[0][tid] = src[(long)(rowg0 + (tid >> 2)) * 256 + (tid & 3)];
  }
  const float4 wv = *(const float4*)&W_in[mm * 4];
  const float  bin = b_in[mm];

  bf16x8 B0[4][4], B1[4][4];
  float bias0[4], bias1[4];
  float c0[8] = {0,0,0,0,0,0,0,0}, c1[8] = {0,0,0,0,0,0,0,0};
  load_frags<3, 3>(pw, 0, 48, w, lane, B0, B1);
#pragma unroll
  for (int g = 0; g < 4; g++){
    int n = 64*g + j;
    float s = (g == 2) ? -2.88539008f : -1.44269504f;
    bias0[g] = eb0[n] * s; bias1[g] = eb1[n] * s;
  }
  __syncthreads();

  unsigned short h0r[8], h1r[8];
  const int xoff = (xr | ((mm >> 3) << 4)) * 8 + (mm & 7);   // A-layout slot for k=mm

  // ================= encoder: 1 barrier/step (cell1 skewed by 1) =================
  for (int t = 0; t < 64; t++){
    int cur = t & 1, nxt = cur ^ 1;
    float xv;
    if (tid < 128)
      xv = src[(long)(rowg0 + (tid >> 2)) * 256 + ((t == 63 ? 63 : t + 1) << 2) + (tid & 3)];
    { // x-projection for rows xr, xr+16
      float4 x0 = *(const float4*)&xsrc[cur][xr * 4];
      float4 x1 = *(const float4*)&xsrc[cur][(xr + 16) * 4];
      float m0 = bin + x0.x*wv.x + x0.y*wv.y + x0.z*wv.z + x0.w*wv.w;
      float m1 = bin + x1.x*wv.x + x1.y*wv.y + x1.z*wv.z + x1.w*wv.w;
      A0[cur][0][xoff] = f2bf(m0);
      A0[cur][1][xoff] = f2bf(m1);
    }
    if (tid < 128) xsrc[nxt][tid] = xv;
    __syncthreads();
    // cell0(t)
    cell_compute<3, 2560, false>(&A0[cur][0][0], B0, nullptr, bias0, c0, h0r, lane, w);
#pragma unroll
    for (int rt = 0; rt < 2; rt++){
      write_h(&A0[nxt][rt][0], 32 + j, quad, h0r + rt * 4);   // recurrent h0
      write_h(&A1[cur][rt][0],      j, quad, h0r + rt * 4);   // feed layer 1
    }
    // cell1(t-1)
    if (t > 0){
      cell_compute<4, 2048, false>(&A1[nxt][0][0], B1, nullptr, bias1, c1, h1r, lane, w);
#pragma unroll
      for (int rt = 0; rt < 2; rt++)
        write_h(&A1[cur][rt][0], 64 + j, quad, h1r + rt * 4); // recurrent h1
    }
  }
  __syncthreads();
  // flush cell1(63): reads A1[1], writes recurrent into A1[0] for decoder t=0
  cell_compute<4, 2048, false>(&A1[1][0][0], B1, nullptr, bias1, c1, h1r, lane, w);
#pragma unroll
  for (int rt = 0; rt < 2; rt++)
    write_h(&A1[0][rt][0], 64 + j, quad, h1r + rt * 4);

  // ================= decoder (2 barriers/step, folded feedback) =================
  load_frags<5, 4>(pw, 112, 192, w, lane, B0, B1);
#pragma unroll
  for (int g = 0; g < 4; g++){
    int n = 64*g + j;
    float s = (g == 2) ? -2.88539008f : -1.44269504f;
    bias0[g] = db0[n] * s; bias1[g] = db1[n] * s;
  }
  const float4 bt4 = *(const float4*)bout;
  const float  cb  = bin + wv.x*bt4.x + wv.y*bt4.y + wv.z*bt4.z + wv.w*bt4.w;
  const float  bo  = (w < 2 && l16 < 4) ? bout[l16] : 0.0f;
  { // mtrg(0) = trg(:,0) @ W_in^T + b_in   (no bout term, no h1 fold at t=0)
    float4 x0 = *(const float4*)&trg[(long)(rowg0 + xr) * 256];
    float4 x1 = *(const float4*)&trg[(long)(rowg0 + xr + 16) * 256];
    float m0 = bin + x0.x*wv.x + x0.y*wv.y + x0.z*wv.z + x0.w*wv.w;
    float m1 = bin + x1.x*wv.x + x1.y*wv.y + x1.z*wv.z + x1.w*wv.w;
    A0[0][0][xoff] = f2bf(m0);
    A0[0][1][xoff] = f2bf(m1);
  }
  // note: A0 kt3,4 (h1 fold region) are still zero from init => correct t=0
  __syncthreads();

  for (int t = 0; t < 64; t++){
    int cur = t & 1, nxt = cur ^ 1;
    { // mtrg(t+1) = trg(:,t) @ W_in^T + (b_in + bout @ W_in^T)  -> A0[nxt]
      float4 x0 = *(const float4*)&trg[(long)(rowg0 + xr) * 256 + t * 4];
      float4 x1 = *(const float4*)&trg[(long)(rowg0 + xr + 16) * 256 + t * 4];
      float m0 = cb + x0.x*wv.x + x0.y*wv.y + x0.z*wv.z + x0.w*wv.w;
      float m1 = cb + x1.x*wv.x + x1.y*wv.y + x1.z*wv.z + x1.w*wv.w;
      A0[nxt][0][xoff] = f2bf(m0);
      A0[nxt][1][xoff] = f2bf(m1);
    }
    // skewed output projection: out(t-1) from h1(t-1) in A0[cur] kt3,4
    if (w < 2 && t > 0){
      const unsigned short* Ah = &A0[cur][w][0];
      bf16x8 a3  = *(const bf16x8*)(Ah + (3 * 64 + lane) * 8);
      bf16x8 a4  = *(const bf16x8*)(Ah + (4 * 64 + lane) * 8);
      bf16x8 bw0 = *(const bf16x8*)(sWoutF + lane * 8);
      bf16x8 bw1 = *(const bf16x8*)(sWoutF + 512 + lane * 8);
      f32x4 po = {bo, bo, bo, bo};
      po = __builtin_amdgcn_mfma_f32_16x16x32_bf16(a3, bw0, po, 0, 0, 0);
      po = __builtin_amdgcn_mfma_f32_16x16x32_bf16(a4, bw1, po, 0, 0, 0);
      if (l16 < 4){
#pragma unroll
        for (int e = 0; e < 4; e++){
          long idx = (long)(rowg0 + w * 16 + quad * 4 + e) * 256 + (t - 1) * 4 + l16;
          out[idx] = po[e] + trg[idx];
        }
      }
    }
    // cell0: K=160 = [mtrg | pad | h0 | h1-fold(LDS-streamed B)]
    cell_compute<4, 2560, true>(&A0[cur][0][0], B0, sFold, bias0, c0, h0r, lane, w);
#pragma unroll
    for (int rt = 0; rt < 2; rt++){
      write_h(&A0[nxt][rt][0], 32 + j, quad, h0r + rt * 4);
      write_h(&A1[cur][rt][0],      j, quad, h0r + rt * 4);
    }
    __syncthreads();                       // barB: h0 visible
    cell_compute<4, 2048, false>(&A1[cur][0][0], B1, nullptr, bias1, c1, h1r, lane, w);
#pragma unroll
    for (int rt = 0; rt < 2; rt++){
      write_h(&A1[nxt][rt][0], 64 + j, quad, h1r + rt * 4);   // recurrent h1
      write_h(&A0[nxt][rt][0], 96 + j, quad, h1r + rt * 4);   // feedback fold region
    }
    __syncthreads();                       // barA': h1/mtrg visible for next step
  }
  // final output column t=63: h1(63) sits in A0[0] kt3,4
  if (w < 2){
    const unsigned short* Ah = &A0[0][w][0];
    bf16x8 a3  = *(const bf16x8*)(Ah + (3 * 64 + lane) * 8);
    bf16x8 a4  = *(const bf16x8*)(Ah + (4 * 64 + lane) * 8);
    bf16x8 bw0 = *(const bf16x8*)(sWoutF + lane * 8);
    bf16x8 bw1 = *(const bf16x8*)(sWoutF + 512 + lane * 8);
    f32x4 po = {bo, bo, bo, bo};
    po = __builtin_amdgcn_mfma_f32_16x16x32_bf16(a3, bw0, po, 0, 0, 0);
    po = __builtin_amdgcn_mfma_f32_16x16x32_bf16(a4, bw1, po, 0, 0, 0);
    if (l16 < 4){
#pragma unroll
      for (int e = 0; e < 4; e++){
        long idx = (long)(rowg0 + w * 16 + quad * 4 + e) * 256 + 63 * 4 + l16;
        out[idx] = po[e] + trg[idx];
      }
    }
  }
}

extern "C" void kernel_launch(void* const* d_in, const int* in_sizes, int n_in,
                              void* d_out, int out_size, void* d_ws, size_t ws_size,
                              hipStream_t stream){
  (void)n_in; (void)out_size; (void)ws_size;
  const float* src   = (const float*)d_in[0];
  const float* trg   = (const float*)d_in[1];
  const float* W_in  = (const float*)d_in[2];
  const float* b_in  = (const float*)d_in[3];
  const float* eWih0 = (const float*)d_in[4];
  const float* eWhh0 = (const float*)d_in[5];
  const float* eb0   = (const float*)d_in[6];
  const float* eWih1 = (const float*)d_in[7];
  const float* eWhh1 = (const float*)d_in[8];
  const float* eb1   = (const float*)d_in[9];
  const float* dWih0 = (const float*)d_in[10];
  const float* dWhh0 = (const float*)d_in[11];
  const float* db0   = (const float*)d_in[12];
  const float* dWih1 = (const float*)d_in[13];
  const float* dWhh1 = (const float*)d_in[14];
  const float* db1   = (const float*)d_in[15];
  const float* Wout  = (const float*)d_in[16];
  const float* bout  = (const float*)d_in[17];
  unsigned short* pw = (unsigned short*)d_ws;          // needs 264,192 bytes

  pack_weights<<<65, 256, 0, stream>>>(eWih0, eWhh0, eWih1, eWhh1,
                                       dWih0, dWhh0, dWih1, dWhh1, Wout, W_in, pw);

  int B    = in_sizes[0] / 256;                        // S*I = 256
  int nblk = B / 32;
  lstm_main<<<nblk, 256, 0, stream>>>(src, trg, W_in, b_in, eb0, eb1, db0, db1,
                                      bout, pw, (float*)d_out);
}

// Round 6
// 433.820 us; speedup vs baseline: 3.8326x; 1.0920x over previous
//
#include <hip/hip_runtime.h>

typedef __bf16 bf16x8 __attribute__((ext_vector_type(8)));
typedef float  f32x4  __attribute__((ext_vector_type(4)));

__device__ __forceinline__ unsigned short f2bf(float x){
  return __builtin_bit_cast(unsigned short, (__bf16)x);   // HW v_cvt on gfx950, RNE
}

// LDS-only barrier: all our inter-wave hazards are LDS ping-pong buffers, so
// wait lgkmcnt(0) only — do NOT drain vmcnt (keeps trg prefetch + out[] store
// acks in flight across the barrier, unlike __syncthreads()).
__device__ __forceinline__ void bar_lds(){
  asm volatile("s_waitcnt lgkmcnt(0)" ::: "memory");
  __builtin_amdgcn_s_barrier();
  asm volatile("" ::: "memory");
}

// ---------------------------------------------------------------------------
// Weight pack: MFMA B-fragment order (bf16), lane holds B[k=kt*32+(lane>>4)*8+jj][n=lane&15].
// Gate weights PRE-SCALED by -log2(e) (i,f,o) or -2*log2(e) (g) so the MFMA
// accumulator is directly the exp2() argument.
// Frag sections: [0,48) encL0 (ntile*3+kt, K: x 0..16|pad|h 32..96)
//                [48,112) encL1 (ntile*4+kt, K: h0 0..64|h1 64..128)
//                [112,160) decL0, [160,224) decL1, [224,226) W_out (N=4 padded to 16, K=64)
// ---------------------------------------------------------------------------
__global__ void pack_weights(const float* __restrict__ eWih0, const float* __restrict__ eWhh0,
                             const float* __restrict__ eWih1, const float* __restrict__ eWhh1,
                             const float* __restrict__ dWih0, const float* __restrict__ dWhh0,
                             const float* __restrict__ dWih1, const float* __restrict__ dWhh1,
                             const float* __restrict__ Wout,
                             unsigned short* __restrict__ out){
  int t = blockIdx.x * 256 + threadIdx.x;
  if (t >= 226 * 64) return;
  int lane = t & 63;
  int f    = t >> 6;
  unsigned short vals[8];
  if (f >= 224){                                       // W_out frags (NOT scaled)
    int kt = f - 224, n = lane & 15;
#pragma unroll
    for (int jj = 0; jj < 8; jj++){
      int k = kt * 32 + (lane >> 4) * 8 + jj;
      vals[jj] = (n < 4) ? f2bf(Wout[n * 64 + k]) : (unsigned short)0;
    }
  } else {
    const float *Wih, *Whh; int kx, ntile, kt;
    if (f < 48)       { Wih=eWih0; Whh=eWhh0; kx=16; ntile=f/3;        kt=f%3; }
    else if (f < 112) { Wih=eWih1; Whh=eWhh1; kx=64; ntile=(f-48)/4;   kt=(f-48)%4; }
    else if (f < 160) { Wih=dWih0; Whh=dWhh0; kx=16; ntile=(f-112)/3;  kt=(f-112)%3; }
    else              { Wih=dWih1; Whh=dWhh1; kx=64; ntile=(f-160)/4;  kt=(f-160)%4; }
    int n    = ntile * 16 + (lane & 15);
    int hoff = (kx == 16) ? 32 : 64;
    // gate index = n/64 = ntile/4; gates i,f,o get -log2(e), gate g gets -2*log2(e)
    float scale = ((ntile >> 2) == 2) ? -2.88539008f : -1.44269504f;
#pragma unroll
    for (int jj = 0; jj < 8; jj++){
      int k = kt * 32 + (lane >> 4) * 8 + jj;
      float v;
      if (k < kx)        v = Wih[n * kx + k];
      else if (k < hoff) v = 0.0f;
      else               v = Whh[n * 64 + (k - hoff)];
      vals[jj] = f2bf(v * scale);
    }
  }
  uint4 o;
  o.x = (unsigned)vals[0] | ((unsigned)vals[1] << 16);
  o.y = (unsigned)vals[2] | ((unsigned)vals[3] << 16);
  o.z = (unsigned)vals[4] | ((unsigned)vals[5] << 16);
  o.w = (unsigned)vals[6] | ((unsigned)vals[7] << 16);
  ((uint4*)out)[f * 64 + lane] = o;
}

// A-layout (per 16-row subtile): elem(m,k) at ((k>>5)*64 + (m | (((k>>3)&3)<<4)))*8 + (k&7)
__device__ __forceinline__ void write_h(unsigned short* buf, int k, int quad,
                                        const unsigned short* h){
  unsigned short* p = buf + (((k >> 5) * 64) + quad * 4 + (((k >> 3) & 3) << 4)) * 8 + (k & 7);
#pragma unroll
  for (int e = 0; e < 4; e++) p[e * 8] = h[e];
}

__device__ __forceinline__ void load_frags(const unsigned short* __restrict__ pw,
                                           int base0, int base1, int w, int lane,
                                           bf16x8 (&B0)[3][4], bf16x8 (&B1)[4][4]){
#pragma unroll
  for (int g = 0; g < 4; g++){
    int nt = 4 * g + w;
#pragma unroll
    for (int kt = 0; kt < 3; kt++)
      B0[kt][g] = *(const bf16x8*)(pw + (((long)(base0 + nt * 3 + kt)) * 64 + lane) * 8);
#pragma unroll
    for (int kt = 0; kt < 4; kt++)
      B1[kt][g] = *(const bf16x8*)(pw + (((long)(base1 + nt * 4 + kt)) * 64 + lane) * 8);
  }
}

// One LSTM cell step for 32 rows (2 row-subtiles of 16, interleaved: 8 indep
// MFMA chains), this wave's 16 j's. acc arrives exp2-ready (pre-scaled weights).
// Single-rcp c-update (common denominator):
//   c2 = [c*(1+ei)(1+eg) + K(1-eg)(1+ef)] / [(1+ef)(1+ei)(1+eg)],  K = 2*log2(e)
//   sig(o)*tanh(c) = (ec-1)/((1+eo)(1+ec)),  ec = exp2(c2) = e^{2c}
template<int KT, int SZ>
__device__ __forceinline__ void cell_compute(const unsigned short* __restrict__ A,
                                             const bf16x8 (&B)[KT][4],
                                             const float (&bias)[4],
                                             float (&c)[8],
                                             unsigned short (&hout)[8],
                                             int lane){
  f32x4 acc[4][2];
#pragma unroll
  for (int g = 0; g < 4; g++){
    f32x4 b = {bias[g], bias[g], bias[g], bias[g]};
    acc[g][0] = b; acc[g][1] = b;
  }
#pragma unroll
  for (int kt = 0; kt < KT; kt++){
    bf16x8 a0 = *(const bf16x8*)(A +      (kt * 64 + lane) * 8);
    bf16x8 a1 = *(const bf16x8*)(A + SZ + (kt * 64 + lane) * 8);
#pragma unroll
    for (int g = 0; g < 4; g++){
      acc[g][0] = __builtin_amdgcn_mfma_f32_16x16x32_bf16(a0, B[kt][g], acc[g][0], 0, 0, 0);
      acc[g][1] = __builtin_amdgcn_mfma_f32_16x16x32_bf16(a1, B[kt][g], acc[g][1], 0, 0, 0);
    }
  }
#pragma unroll
  for (int rt = 0; rt < 2; rt++){
#pragma unroll
    for (int e = 0; e < 4; e++){
      int idx = rt * 4 + e;
      float ei = __builtin_amdgcn_exp2f(acc[0][rt][e]);   // e^{-i}
      float ef = __builtin_amdgcn_exp2f(acc[1][rt][e]);   // e^{-f}
      float eg = __builtin_amdgcn_exp2f(acc[2][rt][e]);   // e^{-2g}
      float eo = __builtin_amdgcn_exp2f(acc[3][rt][e]);   // e^{-o}
      float pf   = 1.0f + ef;
      float pig  = (1.0f + ei) * (1.0f + eg);
      float rden = __builtin_amdgcn_rcpf(pf * pig);
      float num  = fmaf(fmaf(-2.88539008f, eg, 2.88539008f), pf, c[idx] * pig);
      float c2   = num * rden;
      c[idx] = c2;
      float ec  = __builtin_amdgcn_exp2f(c2);             // e^{2c}
      float rot = __builtin_amdgcn_rcpf((1.0f + eo) * (1.0f + ec));
      hout[idx] = f2bf((ec - 1.0f) * rot);                // sig(o)*tanh(c)
    }
  }
}

// ---------------------------------------------------------------------------
// Main: one block = 32 batch rows, full encoder (1 barrier/step, layer-skewed)
// + decoder (4 barriers/step, serial feedback). 4 waves; wave w owns j-slice
// [16w,16w+16) for all 4 gates, both row-subtiles. All barriers are LDS-only
// (raw s_barrier + lgkmcnt), keeping global prefetch/stores in flight.
// ---------------------------------------------------------------------------
__global__ __launch_bounds__(256, 2)
void lstm_main(const float* __restrict__ src, const float* __restrict__ trg,
               const float* __restrict__ W_in, const float* __restrict__ b_in,
               const float* __restrict__ eb0, const float* __restrict__ eb1,
               const float* __restrict__ db0, const float* __restrict__ db1,
               const float* __restrict__ bout,
               const unsigned short* __restrict__ pw,
               float* __restrict__ out){
  __shared__ __align__(16) unsigned short A0[2][2][1536];   // ping-pong, 2 row-subtiles, K=96
  __shared__ __align__(16) unsigned short A1[2][2][2048];   // K=128
  __shared__ __align__(16) float xsrc[2][128];              // per-step x ping-pong (32 rows x 4)
  __shared__ __align__(16) float xfb[128];                  // decoder feedback x
  __shared__ __align__(16) unsigned short sWoutF[1024];     // W_out B-frags (2 x 64 x 8)

  const int tid  = threadIdx.x;
  const int lane = tid & 63;
  const int w    = tid >> 6;
  const int quad = lane >> 4;
  const int l16  = lane & 15;
  const int j    = 16 * w + l16;
  const int rowg0 = blockIdx.x * 32;
  const int mm   = tid & 15;                  // x-proj: this thread's m-unit
  const int xr   = tid >> 4;                  // x-proj: rows xr and xr+16

  // ---- staging ----
  {
    uint4 z; z.x = z.y = z.z = z.w = 0u;
    uint4* a0p = (uint4*)A0;                  // 768 uint4
    uint4* a1p = (uint4*)A1;                  // 1024 uint4
    for (int i = tid; i < 768;  i += 256) a0p[i] = z;
    for (int i = tid; i < 1024; i += 256) a1p[i] = z;
    if (tid < 128) ((uint4*)sWoutF)[tid] = ((const uint4*)pw)[224 * 64 + tid];
    if (tid < 128) xsrc[0][tid] = src[(long)(rowg0 + (tid >> 2)) * 256 + (tid & 3)];
  }
  const float4 wv = *(const float4*)&W_in[mm * 4];
  const float  bin = b_in[mm];

  bf16x8 B0[3][4], B1[4][4];
  float bias0[4], bias1[4];
  float c0[8] = {0,0,0,0,0,0,0,0}, c1[8] = {0,0,0,0,0,0,0,0};
  load_frags(pw, 0, 48, w, lane, B0, B1);
#pragma unroll
  for (int g = 0; g < 4; g++){
    int n = 64*g + j;
    float s = (g == 2) ? -2.88539008f : -1.44269504f;   // match weight pre-scale
    bias0[g] = eb0[n] * s; bias1[g] = eb1[n] * s;
  }
  bar_lds();

  unsigned short h0r[8], h1r[8];
  const int xoff = (xr | ((mm >> 3) << 4)) * 8 + (mm & 7);   // A-layout slot for k=mm

  // ================= encoder: 1 barrier/step (cell1 skewed by 1) =================
  for (int t = 0; t < 64; t++){
    int cur = t & 1, nxt = cur ^ 1;
    float xv;
    if (tid < 128)
      xv = src[(long)(rowg0 + (tid >> 2)) * 256 + ((t == 63 ? 63 : t + 1) << 2) + (tid & 3)];
    { // x-projection for rows xr, xr+16
      float4 x0 = *(const float4*)&xsrc[cur][xr * 4];
      float4 x1 = *(const float4*)&xsrc[cur][(xr + 16) * 4];
      float m0 = bin + x0.x*wv.x + x0.y*wv.y + x0.z*wv.z + x0.w*wv.w;
      float m1 = bin + x1.x*wv.x + x1.y*wv.y + x1.z*wv.z + x1.w*wv.w;
      A0[cur][0][xoff] = f2bf(m0);
      A0[cur][1][xoff] = f2bf(m1);
    }
    if (tid < 128) xsrc[nxt][tid] = xv;
    bar_lds();
    // cell0(t)
    cell_compute<3, 1536>(&A0[cur][0][0], B0, bias0, c0, h0r, lane);
#pragma unroll
    for (int rt = 0; rt < 2; rt++){
      write_h(&A0[nxt][rt][0], 32 + j, quad, h0r + rt * 4);   // recurrent h0
      write_h(&A1[cur][rt][0],      j, quad, h0r + rt * 4);   // feed layer 1
    }
    // cell1(t-1) — inputs written during iter t-1, visible since barrier above
    if (t > 0){
      cell_compute<4, 2048>(&A1[nxt][0][0], B1, bias1, c1, h1r, lane);
#pragma unroll
      for (int rt = 0; rt < 2; rt++)
        write_h(&A1[cur][rt][0], 64 + j, quad, h1r + rt * 4); // recurrent h1
    }
  }
  bar_lds();
  // flush cell1(63): reads A1[1], writes recurrent into A1[0] for decoder t=0
  cell_compute<4, 2048>(&A1[1][0][0], B1, bias1, c1, h1r, lane);
#pragma unroll
  for (int rt = 0; rt < 2; rt++)
    write_h(&A1[0][rt][0], 64 + j, quad, h1r + rt * 4);

  // ================= decoder =================
  load_frags(pw, 112, 160, w, lane, B0, B1);
#pragma unroll
  for (int g = 0; g < 4; g++){
    int n = 64*g + j;
    float s = (g == 2) ? -2.88539008f : -1.44269504f;
    bias0[g] = db0[n] * s; bias1[g] = db1[n] * s;
  }
  const float bo = (w < 2 && l16 < 4) ? bout[l16] : 0.0f;
  if (tid < 128) xfb[tid] = trg[(long)(rowg0 + (tid >> 2)) * 256 + (tid & 3)];
  bar_lds();

  for (int t = 0; t < 64; t++){
    int cur = t & 1, nxt = cur ^ 1;
    float tpre[4];
    if (w < 2 && l16 < 4){
#pragma unroll
      for (int e = 0; e < 4; e++)
        tpre[e] = trg[(long)(rowg0 + w * 16 + quad * 4 + e) * 256 + t * 4 + l16];
    }
    { // m = x @ W_in^T + b_in
      float4 x0 = *(const float4*)&xfb[xr * 4];
      float4 x1 = *(const float4*)&xfb[(xr + 16) * 4];
      float m0 = bin + x0.x*wv.x + x0.y*wv.y + x0.z*wv.z + x0.w*wv.w;
      float m1 = bin + x1.x*wv.x + x1.y*wv.y + x1.z*wv.z + x1.w*wv.w;
      A0[cur][0][xoff] = f2bf(m0);
      A0[cur][1][xoff] = f2bf(m1);
    }
    bar_lds();                             // barA
    cell_compute<3, 1536>(&A0[cur][0][0], B0, bias0, c0, h0r, lane);
#pragma unroll
    for (int rt = 0; rt < 2; rt++){
      write_h(&A0[nxt][rt][0], 32 + j, quad, h0r + rt * 4);
      write_h(&A1[cur][rt][0],      j, quad, h0r + rt * 4);
    }
    bar_lds();                             // barB
    cell_compute<4, 2048>(&A1[cur][0][0], B1, bias1, c1, h1r, lane);
#pragma unroll
    for (int rt = 0; rt < 2; rt++)
      write_h(&A1[nxt][rt][0], 64 + j, quad, h1r + rt * 4);
    bar_lds();                             // barC: h2 visible
    if (w < 2){                            // MFMA out-projection, wave w = row-subtile w
      const unsigned short* Ah = &A1[nxt][w][0];
      bf16x8 a2 = *(const bf16x8*)(Ah + (2 * 64 + lane) * 8);
      bf16x8 a3 = *(const bf16x8*)(Ah + (3 * 64 + lane) * 8);
      bf16x8 bw0 = *(const bf16x8*)(sWoutF + lane * 8);
      bf16x8 bw1 = *(const bf16x8*)(sWoutF + 512 + lane * 8);
      f32x4 po = {bo, bo, bo, bo};
      po = __builtin_amdgcn_mfma_f32_16x16x32_bf16(a2, bw0, po, 0, 0, 0);
      po = __builtin_amdgcn_mfma_f32_16x16x32_bf16(a3, bw1, po, 0, 0, 0);
      if (l16 < 4){
#pragma unroll
        for (int e = 0; e < 4; e++){
          int row = w * 16 + quad * 4 + e;
          float v = po[e] + tpre[e];
          out[(long)(rowg0 + row) * 256 + t * 4 + l16] = v;
          xfb[row * 4 + l16] = v;
        }
      }
    }
    bar_lds();                             // barD: xfb visible
  }
}

extern "C" void kernel_launch(void* const* d_in, const int* in_sizes, int n_in,
                              void* d_out, int out_size, void* d_ws, size_t ws_size,
                              hipStream_t stream){
  (void)n_in; (void)out_size; (void)ws_size;
  const float* src   = (const float*)d_in[0];
  const float* trg   = (const float*)d_in[1];
  const float* W_in  = (const float*)d_in[2];
  const float* b_in  = (const float*)d_in[3];
  const float* eWih0 = (const float*)d_in[4];
  const float* eWhh0 = (const float*)d_in[5];
  const float* eb0   = (const float*)d_in[6];
  const float* eWih1 = (const float*)d_in[7];
  const float* eWhh1 = (const float*)d_in[8];
  const float* eb1   = (const float*)d_in[9];
  const float* dWih0 = (const float*)d_in[10];
  const float* dWhh0 = (const float*)d_in[11];
  const float* db0   = (const float*)d_in[12];
  const float* dWih1 = (const float*)d_in[13];
  const float* dWhh1 = (const float*)d_in[14];
  const float* db1   = (const float*)d_in[15];
  const float* Wout  = (const float*)d_in[16];
  const float* bout  = (const float*)d_in[17];
  unsigned short* pw = (unsigned short*)d_ws;          // needs 231,424 bytes

  pack_weights<<<57, 256, 0, stream>>>(eWih0, eWhh0, eWih1, eWhh1,
                                       dWih0, dWhh0, dWih1, dWhh1, Wout, pw);

  int B    = in_sizes[0] / 256;                        // S*I = 256
  int nblk = B / 32;
  lstm_main<<<nblk, 256, 0, stream>>>(src, trg, W_in, b_in, eb0, eb1, db0, db1,
                                      bout, pw, (float*)d_out);
}